// Round 8
// baseline (349.292 us; speedup 1.0000x reference)
//
#include <hip/hip_runtime.h>
#include <stdint.h>

#define HD   256
#define SEQ  4096
#define NB   4
#define NROW (NB * SEQ)   // 16384

typedef __attribute__((ext_vector_type(8))) short short8;
typedef __attribute__((ext_vector_type(4))) float f32x4;
typedef __attribute__((ext_vector_type(16))) float f32x16;
typedef _Float16 v8h __attribute__((ext_vector_type(8)));

__device__ __forceinline__ unsigned short f2bf(float f) {
  union { float f; unsigned u; } v; v.f = f;
  unsigned u = v.u;
  u += 0x7fffu + ((u >> 16) & 1u);
  return (unsigned short)(u >> 16);
}
__device__ __forceinline__ float bf2f(unsigned short h) {
  union { float f; unsigned u; } v; v.u = ((unsigned)h) << 16;
  return v.f;
}
__device__ __forceinline__ unsigned short f2h(float f) {
  union { _Float16 h; unsigned short u; } v;
  v.h = (_Float16)f;
  return v.u;
}

__device__ __forceinline__ f32x4 mfma16(short8 a, short8 b, f32x4 c) {
  return __builtin_amdgcn_mfma_f32_16x16x32_bf16(a, b, c, 0, 0, 0);
}
__device__ __forceinline__ f32x16 mfma32h(v8h a, v8h b, f32x16 c) {
  return __builtin_amdgcn_mfma_f32_32x32x16_f16(a, b, c, 0, 0, 0);
}

__device__ __forceinline__ void gload_lds16(const void* g, void* l) {
  __builtin_amdgcn_global_load_lds((const __attribute__((address_space(1))) void*)g,
                                   (__attribute__((address_space(3))) void*)l,
                                   16, 0, 0);
}

// pack two f32 -> u32 of two fp16 (elem0 in low 16)
__device__ __forceinline__ unsigned pk2h(float a, float b) {
  return (unsigned)f2h(a) | ((unsigned)f2h(b) << 16);
}

// ---------------------------------------------------------------------------
// Kernel 0: split x (f32) into bf16 hi/lo once.
// ---------------------------------------------------------------------------
__global__ __launch_bounds__(256) void prep_x_kernel(
    const float* __restrict__ x,
    unsigned short* __restrict__ xh, unsigned short* __restrict__ xl)
{
  int i = blockIdx.x * 256 + threadIdx.x;      // 8 elems per thread
  const float* p = x + i * 8;
  f32x4 a0 = *(const f32x4*)p;
  f32x4 a1 = *(const f32x4*)(p + 4);
  short8 hh, ll;
#pragma unroll
  for (int j = 0; j < 4; ++j) {
    unsigned short h0 = f2bf(a0[j]);
    hh[j]     = (short)h0;
    ll[j]     = (short)f2bf(a0[j] - bf2f(h0));
    unsigned short h1 = f2bf(a1[j]);
    hh[4 + j] = (short)h1;
    ll[4 + j] = (short)f2bf(a1[j] - bf2f(h1));
  }
  *(short8*)(xh + i * 8) = hh;
  *(short8*)(xl + i * 8) = ll;
}

// ---------------------------------------------------------------------------
// Kernel 1: transpose + hi/lo split the weight matrices (bf16).
// ---------------------------------------------------------------------------
__global__ __launch_bounds__(256) void prep_w_kernel(
    const float* __restrict__ Wq, const float* __restrict__ Wk,
    const float* __restrict__ Wv,
    unsigned short* __restrict__ WTh, unsigned short* __restrict__ WTl)
{
  int flat = blockIdx.x * 256 + threadIdx.x;   // 0 .. 3*65536-1
  int mat = flat >> 16;
  int e   = flat & 65535;
  int o   = e >> 8;
  int k   = e & 255;
  const float* W = (mat == 0) ? Wq : (mat == 1) ? Wk : Wv;
  float v = W[k * 256 + o];
  unsigned short h = f2bf(v);
  WTh[flat] = h;
  WTl[flat] = f2bf(v - bf2f(h));
}

// ---------------------------------------------------------------------------
// Kernel 2: QKV projection via split-bf16 3-product MFMA; outputs fp16.
// mat 0 -> Qf [row][h], 1 -> Kf [row][h], 2 -> VT [b][h][s] (transposed).
// ---------------------------------------------------------------------------
__global__ __launch_bounds__(256) void proj_kernel(
    const unsigned short* __restrict__ xh, const unsigned short* __restrict__ xl,
    const unsigned short* __restrict__ WTh, const unsigned short* __restrict__ WTl,
    const float* __restrict__ bq, const float* __restrict__ bk,
    const float* __restrict__ bv,
    unsigned short* __restrict__ Qf, unsigned short* __restrict__ Kf,
    unsigned short* __restrict__ VT)
{
  const int mat = blockIdx.y;
  const int r0  = blockIdx.x << 6;     // 64-row tile
  const int tid = threadIdx.x;
  const int w    = tid >> 6;
  const int lane = tid & 63;
  const int lr   = lane & 15;
  const int hi4  = lane >> 4;
  const int r4   = hi4 << 2;

  const unsigned short* wth = WTh + (mat << 16);
  const unsigned short* wtl = WTl + (mat << 16);

  f32x4 acc[4][4] = {};

#pragma unroll
  for (int ks = 0; ks < 8; ++ks) {
    short8 ah[4], al[4];
#pragma unroll
    for (int m = 0; m < 4; ++m) {
      int off = (r0 + (m << 4) + lr) * 256 + (ks << 5) + (hi4 << 3);
      ah[m] = *(const short8*)(xh + off);
      al[m] = *(const short8*)(xl + off);
    }
#pragma unroll
    for (int n = 0; n < 4; ++n) {
      int o = (w << 6) + (n << 4) + lr;
      short8 bh = *(const short8*)(wth + o * 256 + (ks << 5) + (hi4 << 3));
      short8 bl = *(const short8*)(wtl + o * 256 + (ks << 5) + (hi4 << 3));
#pragma unroll
      for (int m = 0; m < 4; ++m) acc[m][n] = mfma16(ah[m], bh, acc[m][n]);
#pragma unroll
      for (int m = 0; m < 4; ++m) acc[m][n] = mfma16(al[m], bh, acc[m][n]);
#pragma unroll
      for (int m = 0; m < 4; ++m) acc[m][n] = mfma16(ah[m], bl, acc[m][n]);
    }
  }

  const float* bias = (mat == 0) ? bq : (mat == 1) ? bk : bv;
#pragma unroll
  for (int n = 0; n < 4; ++n) {
    int col = (w << 6) + (n << 4) + lr;
    float bb = bias[col];
#pragma unroll
    for (int m = 0; m < 4; ++m) {
#pragma unroll
      for (int reg = 0; reg < 4; ++reg) {
        int row = r0 + (m << 4) + r4 + reg;     // global row in [0,16384)
        float val = acc[m][n][reg] + bb;
        unsigned short h = f2h(val);
        if (mat == 0) {
          Qf[row * 256 + col] = h;
        } else if (mat == 1) {
          Kf[row * 256 + col] = h;
        } else {
          int b = row >> 12, s = row & 4095;
          VT[(b << 20) + (col << 12) + s] = h;
        }
      }
    }
  }
}

// ---------------------------------------------------------------------------
// Kernel 3: causal flash attention, 32x32x16 MFMA, BQ=128, SWAPPED QK^T.
// S^T = mfma(K, Q): lane owns q=(lane&31); k lives in regs -> softmax state
// is 2 scalars/lane, P stays in registers (pack + shfl_xor(32) exchange).
// Q read from global (anti-hoisted), K/V staged in 64KB LDS -> 2 blocks/CU.
// Grid 64*nch: (batch, pair p, chunk s of the pair's 66 tiles).
// ---------------------------------------------------------------------------
__global__ __launch_bounds__(256, 2) void attn_kernel(
    const unsigned short* __restrict__ Qf, const unsigned short* __restrict__ Kf,
    const unsigned short* __restrict__ VT,
    unsigned short* __restrict__ Opart, float* __restrict__ Mpart,
    float* __restrict__ Lpart, int nch)
{
  __shared__ __align__(16) unsigned short sK[64 * 256];
  __shared__ __align__(16) unsigned short sV[256 * 64];

  const int bx    = blockIdx.x;
  const int xcd   = bx & 7;
  const int batch = xcd >> 1;
  const int e     = xcd & 1;
  const int rnk   = bx >> 3;
  const int p     = rnk & 15;
  const int s     = ((rnk >> 4) << 1) | e;     // 0..nch-1
  const int jA = p, jB = 31 - p;
  const int LA = 2 * (p + 1);                  // tiles in segment A
  const int g0 = (66 * s) / nch;
  const int g1 = (66 * (s + 1)) / nch;

  const int tid  = threadIdx.x;
  const int w    = tid >> 6;
  const int lane = tid & 63;
  const int lc   = lane & 31;
  const int hi   = lane >> 5;

  const unsigned short* Kf_b = Kf + (batch << 20);
  const unsigned short* VT_b = VT + (batch << 20);

  auto stage = [&](int kt) {
#pragma unroll
    for (int it = 0; it < 8; ++it) {
      int id = it * 256 + tid;
      int kr = id >> 5, cb = id & 31;
      gload_lds16(Kf_b + (((kt << 6) + kr) << 8) + (((cb ^ kr) & 31) << 3),
                  sK + id * 8);
      int hd = id >> 3, cb2 = id & 7;
      gload_lds16(VT_b + (hd << 12) + (kt << 6) + (((cb2 ^ (hd >> 2)) & 7) << 3),
                  sV + id * 8);
    }
  };

  f32x16 oacc[8];
  float m_, accl;
  auto resetAcc = [&]() {
    m_ = -1e30f; accl = 0.f;
#pragma unroll
    for (int n = 0; n < 8; ++n)
#pragma unroll
      for (int r = 0; r < 16; ++r) oacc[n][r] = 0.f;
  };

  auto flush = [&](int j) {
    int slot = (((batch << 5) + j)) * nch + s;
    unsigned short* Op = Opart + (size_t)slot * (128 * 256);
    float lt  = accl + __shfl_xor(accl, 32);
    float inv = (lt > 0.f) ? (1.0f / lt) : 0.f;
    float invr[16];
#pragma unroll
    for (int r = 0; r < 16; ++r)
      invr[r] = __shfl(inv, (r & 3) + ((r >> 2) << 3) + (hi << 2));
#pragma unroll
    for (int n = 0; n < 8; ++n) {
#pragma unroll
      for (int r = 0; r < 16; ++r) {
        int row = (w << 5) + (r & 3) + ((r >> 2) << 3) + (hi << 2);
        Op[row * 256 + (n << 5) + lc] = f2h(oacc[n][r] * invr[r]);
      }
    }
    if (lane < 32) {
      Mpart[slot * 128 + (w << 5) + lc] = m_;
      Lpart[slot * 128 + (w << 5) + lc] = lt;
    }
  };
  auto writeEmpty = [&](int j) {
    int slot = (((batch << 5) + j)) * nch + s;
    if (lane < 32) {
      Mpart[slot * 128 + (w << 5) + lc] = -1e30f;
      Lpart[slot * 128 + (w << 5) + lc] = 0.f;
    }
  };

  const int aEnd   = (g1 < LA) ? g1 : LA;
  const bool hasA  = g0 < aEnd;
  const int bStart = (g0 > LA) ? g0 : LA;
  const bool hasB  = bStart < g1;

  resetAcc();
  int curj = hasA ? jA : jB;

  for (int g = g0; g < g1; ++g) {
    const bool inA = g < LA;
    const int j  = inA ? jA : jB;
    const int kt = inA ? g : (g - LA);

    if (j != curj) {           // crossed A->B boundary
      flush(jA);
      resetAcc();
      curj = jB;
    }

    stage(kt);
    __syncthreads();           // K/V staged (vmcnt drained), prev reads done

    // ---- Q base for this wave's q-col (anti-hoisted so loads re-issue)
    int qrow = (batch << 12) + (j << 7) + (w << 5) + lc;
    uintptr_t qv = (uintptr_t)Qf + ((size_t)qrow << 9) + (hi << 4);
    asm volatile("" : "+v"(qv));
    const unsigned short* qp = (const unsigned short*)qv;

    // ---- QK^T (swapped): S^T[k][q], rows k in regs, col q = lane&31
    f32x16 s0, s1;
#pragma unroll
    for (int r = 0; r < 16; ++r) { s0[r] = 0.f; s1[r] = 0.f; }
    __builtin_amdgcn_s_setprio(1);
#pragma unroll
    for (int ks = 0; ks < 16; ++ks) {
      int c = (ks << 1) + hi;
      v8h qa  = *(const v8h*)(qp + (ks << 4));
      v8h kb0 = *(const v8h*)(sK + (lc << 8) + (((c ^ lc) & 31) << 3));
      v8h kb1 = *(const v8h*)(sK + ((32 + lc) << 8) + (((c ^ lc) & 31) << 3));
      s0 = mfma32h(kb0, qa, s0);
      s1 = mfma32h(kb1, qa, s1);
    }
    __builtin_amdgcn_s_setprio(0);

    // ---- causal mask: k = kt*64 + (r&3)+8*(r>>2)+4*hi (+32 for s1)
    const int qg = (j << 7) + (w << 5) + lc;     // sequence-local q
    if ((kt << 6) + 63 > (j << 7) + (w << 5)) {
#pragma unroll
      for (int r = 0; r < 16; ++r) {
        int kl = (kt << 6) + (r & 3) + ((r >> 2) << 3) + (hi << 2);
        if (kl > qg)      s0[r] = -3e38f;
        if (kl + 32 > qg) s1[r] = -3e38f;
      }
    }

    // ---- row max: in-lane over 32 regs + pair-lane combine
    float mx = fmaxf(s0[0], s1[0]);
#pragma unroll
    for (int r = 1; r < 16; ++r) mx = fmaxf(mx, fmaxf(s0[r], s1[r]));
    mx = fmaxf(mx, __shfl_xor(mx, 32));

    // ---- defer-max rescale (THR = 8)
    if (__any(mx > m_ + 8.0f)) {
      float mn = fmaxf(m_, mx);
      float sc = __expf(m_ - mn);
      m_ = mn;
      accl *= sc;
#pragma unroll
      for (int r = 0; r < 16; ++r) {
        float scr = __shfl(sc, (r & 3) + ((r >> 2) << 3) + (hi << 2));
#pragma unroll
        for (int n = 0; n < 8; ++n) oacc[n][r] *= scr;
      }
    }

    // ---- P = exp(S^T - m), in place; l partial sum (lane-local)
#pragma unroll
    for (int r = 0; r < 16; ++r) {
      s0[r] = __expf(s0[r] - m_);
      s1[r] = __expf(s1[r] - m_);
      accl += s0[r] + s1[r];
    }

    // ---- PV: build A-frags in-register (pack + shfl_xor32), then MFMA
    __builtin_amdgcn_s_setprio(1);
#pragma unroll
    for (int half = 0; half < 2; ++half) {
      const f32x16& ps = half ? s1 : s0;
#pragma unroll
      for (int t2 = 0; t2 < 2; ++t2) {          // ks2 = half*2 + t2
        int b = t2 << 3;
        unsigned X0 = pk2h(ps[b + 0], ps[b + 1]);
        unsigned X1 = pk2h(ps[b + 2], ps[b + 3]);
        unsigned Y0 = pk2h(ps[b + 4], ps[b + 5]);
        unsigned Y1 = pk2h(ps[b + 6], ps[b + 7]);
        unsigned xs0 = (unsigned)__shfl_xor((int)X0, 32);
        unsigned xs1 = (unsigned)__shfl_xor((int)X1, 32);
        unsigned ys0 = (unsigned)__shfl_xor((int)Y0, 32);
        unsigned ys1 = (unsigned)__shfl_xor((int)Y1, 32);
        union { unsigned u[4]; v8h h; } pa;
        pa.u[0] = hi ? ys0 : X0;
        pa.u[1] = hi ? ys1 : X1;
        pa.u[2] = hi ? Y0 : xs0;
        pa.u[3] = hi ? Y1 : xs1;
        int ks2 = (half << 1) + t2;
        int c   = (ks2 << 1) + hi;
#pragma unroll
        for (int n = 0; n < 8; ++n) {
          int hd = (n << 5) + lc;
          v8h vb = *(const v8h*)(sV + (hd << 6) + (((c ^ (hd >> 2)) & 7) << 3));
          oacc[n] = mfma32h(pa.h, vb, oacc[n]);
        }
      }
    }
    __builtin_amdgcn_s_setprio(0);

    __syncthreads();           // compute done; buffers free for next stage
  }

  flush(curj);
  if (!hasA) writeEmpty(jA);
  if (!hasB) writeEmpty(jB);
}

// ---------------------------------------------------------------------------
// Kernel 4: merge the nch chunk-partials per q-row (two-pass, no arrays).
// ---------------------------------------------------------------------------
__global__ __launch_bounds__(256) void merge_kernel(
    const unsigned short* __restrict__ Opart, const float* __restrict__ Mpart,
    const float* __restrict__ Lpart, float* __restrict__ out, int nch)
{
  int t = blockIdx.x * 256 + threadIdx.x;     // row*32 + c8
  int row = t >> 5, c8 = t & 31;
  int batch = row >> 12, wi = row & 4095;
  int j = wi >> 7, rloc = wi & 127;
  int sbase = ((batch << 5) + j) * nch;

  float M = -1e30f;
  for (int i = 0; i < nch; ++i)
    M = fmaxf(M, Mpart[(sbase + i) * 128 + rloc]);

  float denom = 0.f;
  float r8[8] = {0.f, 0.f, 0.f, 0.f, 0.f, 0.f, 0.f, 0.f};
  for (int i = 0; i < nch; ++i) {
    float mi = Mpart[(sbase + i) * 128 + rloc];
    float li = Lpart[(sbase + i) * 128 + rloc];
    float wgt = __expf(mi - M) * li;
    denom += wgt;
    const unsigned short* Op =
        Opart + ((size_t)(sbase + i) * 128 + rloc) * 256 + (c8 << 3);
    v8h v = *(const v8h*)Op;
#pragma unroll
    for (int q = 0; q < 8; ++q) r8[q] += wgt * (float)v[q];
  }
  float inv = 1.0f / denom;
  float* op = out + (size_t)row * 256 + (c8 << 3);
  f32x4 r0, r1;
#pragma unroll
  for (int q = 0; q < 4; ++q) { r0[q] = r8[q] * inv; r1[q] = r8[4 + q] * inv; }
  *(f32x4*)op = r0;
  *(f32x4*)(op + 4) = r1;
}

// ---------------------------------------------------------------------------
extern "C" void kernel_launch(void* const* d_in, const int* in_sizes, int n_in,
                              void* d_out, int out_size, void* d_ws, size_t ws_size,
                              hipStream_t stream) {
  (void)in_sizes; (void)n_in; (void)out_size;
  const float* x  = (const float*)d_in[0];
  const float* Wq = (const float*)d_in[1];
  const float* bq = (const float*)d_in[2];
  const float* Wk = (const float*)d_in[3];
  const float* bk = (const float*)d_in[4];
  const float* Wv = (const float*)d_in[5];
  const float* bv = (const float*)d_in[6];
  float* out = (float*)d_out;

  // choose chunk count by workspace budget
  const size_t QKV = (size_t)NROW * HD * 2;            // 8 MB each
  auto need = [&](int nch) {
    size_t slots = (size_t)128 * nch;
    size_t ml    = slots * 128 * 4 * 2;
    size_t opart = slots * 128 * 256 * 2;
    size_t prep  = 2 * QKV + 2 * (size_t)(3 * 65536 * 2);  // xh,xl,WTh,WTl
    size_t region = opart > prep ? opart : prep;
    return 3 * QKV + ml + region;
  };
  int nch = (ws_size >= need(8)) ? 8 : 4;

  const size_t slots = (size_t)128 * nch;
  unsigned short* Qf = (unsigned short*)d_ws;                // [16384][256] fp16
  unsigned short* Kf = Qf + (size_t)NROW * HD;
  unsigned short* VT = Kf + (size_t)NROW * HD;               // [4][256][4096]
  float* Mpart = (float*)(VT + (size_t)NROW * HD);           // [slots][128]
  float* Lpart = Mpart + slots * 128;
  // overlap region: prep buffers (dead after proj) share space with Opart
  unsigned short* regionBase = (unsigned short*)(Lpart + slots * 128);
  unsigned short* xh  = regionBase;                          // bf16 [16384][256]
  unsigned short* xl  = xh + (size_t)NROW * HD;
  unsigned short* WTh = xl + (size_t)NROW * HD;              // [3][256][256]
  unsigned short* WTl = WTh + 3 * 65536;
  unsigned short* Opart = regionBase;                        // [slots][128][256]

  hipLaunchKernelGGL(prep_x_kernel, dim3(2048), dim3(256), 0, stream,
                     x, xh, xl);
  hipLaunchKernelGGL(prep_w_kernel, dim3(768), dim3(256), 0, stream,
                     Wq, Wk, Wv, WTh, WTl);
  hipLaunchKernelGGL(proj_kernel, dim3(256, 3), dim3(256), 0, stream,
                     xh, xl, WTh, WTl, bq, bk, bv, Qf, Kf, VT);
  hipLaunchKernelGGL(attn_kernel, dim3(64 * nch), dim3(256), 0, stream,
                     Qf, Kf, VT, Opart, Mpart, Lpart, nch);
  hipLaunchKernelGGL(merge_kernel, dim3(2048), dim3(256), 0, stream,
                     Opart, Mpart, Lpart, out, nch);
}

// Round 9
// 233.684 us; speedup vs baseline: 1.4947x; 1.4947x over previous
//
#include <hip/hip_runtime.h>
#include <stdint.h>

#define HD   256
#define SEQ  4096
#define NB   4
#define NROW (NB * SEQ)   // 16384
#define SLOTS_PER_BATCH 144   // sum over j of ceil((j+1)/4), j=0..31

typedef __attribute__((ext_vector_type(8))) short short8;
typedef __attribute__((ext_vector_type(4))) float f32x4;
typedef __attribute__((ext_vector_type(16))) float f32x16;
typedef _Float16 v8h __attribute__((ext_vector_type(8)));

__device__ __forceinline__ unsigned short f2bf(float f) {
  union { float f; unsigned u; } v; v.f = f;
  unsigned u = v.u;
  u += 0x7fffu + ((u >> 16) & 1u);
  return (unsigned short)(u >> 16);
}
__device__ __forceinline__ float bf2f(unsigned short h) {
  union { float f; unsigned u; } v; v.u = ((unsigned)h) << 16;
  return v.f;
}
__device__ __forceinline__ unsigned short f2h(float f) {
  union { _Float16 h; unsigned short u; } v;
  v.h = (_Float16)f;
  return v.u;
}

__device__ __forceinline__ f32x4 mfma16(short8 a, short8 b, f32x4 c) {
  return __builtin_amdgcn_mfma_f32_16x16x32_bf16(a, b, c, 0, 0, 0);
}
__device__ __forceinline__ f32x16 mfma32h(v8h a, v8h b, f32x16 c) {
  return __builtin_amdgcn_mfma_f32_32x32x16_f16(a, b, c, 0, 0, 0);
}

__device__ __forceinline__ void gload_lds16(const void* g, void* l) {
  __builtin_amdgcn_global_load_lds((const __attribute__((address_space(1))) void*)g,
                                   (__attribute__((address_space(3))) void*)l,
                                   16, 0, 0);
}

// pack two f32 -> u32 of two fp16 (elem0 in low 16)
__device__ __forceinline__ unsigned pk2h(float a, float b) {
  return (unsigned)f2h(a) | ((unsigned)f2h(b) << 16);
}

// ---------------------------------------------------------------------------
// Kernel 0: split x (f32) into bf16 hi/lo once.
// ---------------------------------------------------------------------------
__global__ __launch_bounds__(256) void prep_x_kernel(
    const float* __restrict__ x,
    unsigned short* __restrict__ xh, unsigned short* __restrict__ xl)
{
  int i = blockIdx.x * 256 + threadIdx.x;      // 8 elems per thread
  const float* p = x + i * 8;
  f32x4 a0 = *(const f32x4*)p;
  f32x4 a1 = *(const f32x4*)(p + 4);
  short8 hh, ll;
#pragma unroll
  for (int j = 0; j < 4; ++j) {
    unsigned short h0 = f2bf(a0[j]);
    hh[j]     = (short)h0;
    ll[j]     = (short)f2bf(a0[j] - bf2f(h0));
    unsigned short h1 = f2bf(a1[j]);
    hh[4 + j] = (short)h1;
    ll[4 + j] = (short)f2bf(a1[j] - bf2f(h1));
  }
  *(short8*)(xh + i * 8) = hh;
  *(short8*)(xl + i * 8) = ll;
}

// ---------------------------------------------------------------------------
// Kernel 1: transpose + hi/lo split the weight matrices (bf16).
// ---------------------------------------------------------------------------
__global__ __launch_bounds__(256) void prep_w_kernel(
    const float* __restrict__ Wq, const float* __restrict__ Wk,
    const float* __restrict__ Wv,
    unsigned short* __restrict__ WTh, unsigned short* __restrict__ WTl)
{
  int flat = blockIdx.x * 256 + threadIdx.x;   // 0 .. 3*65536-1
  int mat = flat >> 16;
  int e   = flat & 65535;
  int o   = e >> 8;
  int k   = e & 255;
  const float* W = (mat == 0) ? Wq : (mat == 1) ? Wk : Wv;
  float v = W[k * 256 + o];
  unsigned short h = f2bf(v);
  WTh[flat] = h;
  WTl[flat] = f2bf(v - bf2f(h));
}

// ---------------------------------------------------------------------------
// Kernel 2: QKV projection via split-bf16 3-product MFMA; outputs fp16.
// mat 0 -> Qf [row][h], 1 -> Kf [row][h], 2 -> VT [b][h][s] (transposed).
// ---------------------------------------------------------------------------
__global__ __launch_bounds__(256) void proj_kernel(
    const unsigned short* __restrict__ xh, const unsigned short* __restrict__ xl,
    const unsigned short* __restrict__ WTh, const unsigned short* __restrict__ WTl,
    const float* __restrict__ bq, const float* __restrict__ bk,
    const float* __restrict__ bv,
    unsigned short* __restrict__ Qf, unsigned short* __restrict__ Kf,
    unsigned short* __restrict__ VT)
{
  const int mat = blockIdx.y;
  const int r0  = blockIdx.x << 6;     // 64-row tile
  const int tid = threadIdx.x;
  const int w    = tid >> 6;
  const int lane = tid & 63;
  const int lr   = lane & 15;
  const int hi4  = lane >> 4;
  const int r4   = hi4 << 2;

  const unsigned short* wth = WTh + (mat << 16);
  const unsigned short* wtl = WTl + (mat << 16);

  f32x4 acc[4][4] = {};

#pragma unroll
  for (int ks = 0; ks < 8; ++ks) {
    short8 ah[4], al[4];
#pragma unroll
    for (int m = 0; m < 4; ++m) {
      int off = (r0 + (m << 4) + lr) * 256 + (ks << 5) + (hi4 << 3);
      ah[m] = *(const short8*)(xh + off);
      al[m] = *(const short8*)(xl + off);
    }
#pragma unroll
    for (int n = 0; n < 4; ++n) {
      int o = (w << 6) + (n << 4) + lr;
      short8 bh = *(const short8*)(wth + o * 256 + (ks << 5) + (hi4 << 3));
      short8 bl = *(const short8*)(wtl + o * 256 + (ks << 5) + (hi4 << 3));
#pragma unroll
      for (int m = 0; m < 4; ++m) acc[m][n] = mfma16(ah[m], bh, acc[m][n]);
#pragma unroll
      for (int m = 0; m < 4; ++m) acc[m][n] = mfma16(al[m], bh, acc[m][n]);
#pragma unroll
      for (int m = 0; m < 4; ++m) acc[m][n] = mfma16(ah[m], bl, acc[m][n]);
    }
  }

  const float* bias = (mat == 0) ? bq : (mat == 1) ? bk : bv;
#pragma unroll
  for (int n = 0; n < 4; ++n) {
    int col = (w << 6) + (n << 4) + lr;
    float bb = bias[col];
#pragma unroll
    for (int m = 0; m < 4; ++m) {
#pragma unroll
      for (int reg = 0; reg < 4; ++reg) {
        int row = r0 + (m << 4) + r4 + reg;     // global row in [0,16384)
        float val = acc[m][n][reg] + bb;
        unsigned short h = f2h(val);
        if (mat == 0) {
          Qf[row * 256 + col] = h;
        } else if (mat == 1) {
          Kf[row * 256 + col] = h;
        } else {
          int b = row >> 12, s = row & 4095;
          VT[(b << 20) + (col << 12) + s] = h;
        }
      }
    }
  }
}

// ---------------------------------------------------------------------------
// Kernel 3: causal flash attention, 32x32x16 MFMA, BQ=128, swapped QK^T,
// in-register P. Grid: 576 blocks = (batch = bx&3, rank = bx>>2 -> (j, c)).
// Block (j,c) processes kt in [8c, min(8c+8, 2j+2)) -- fixed-size contiguous
// chunks so ALL blocks sweep kt in lockstep from aligned starts: active K/V
// window ~8 tiles (512 KB) per batch + Q (2 MB) stays L2-resident.
// LDS 64 KB (sK+sV), 2 blocks/CU; Q read from global per iter (anti-hoisted).
// ---------------------------------------------------------------------------
__global__ __launch_bounds__(256, 2) void attn_kernel(
    const unsigned short* __restrict__ Qf, const unsigned short* __restrict__ Kf,
    const unsigned short* __restrict__ VT,
    unsigned short* __restrict__ Opart, float* __restrict__ Mpart,
    float* __restrict__ Lpart)
{
  __shared__ __align__(16) unsigned short sK[64 * 256];
  __shared__ __align__(16) unsigned short sV[256 * 64];

  const int bx    = blockIdx.x;
  const int batch = bx & 3;        // constant per XCD (bx%8 fixed -> bx&3 fixed)
  const int rk    = bx >> 2;       // 0..143
  // decode rank -> (j, c): chunk c of q-tile j (prefix-sum walk, scalar)
  int j = 0, pj = 0;
  while (rk >= pj + ((j + 4) >> 2)) { pj += (j + 4) >> 2; ++j; }
  const int c   = rk - pj;
  const int kt0 = c << 3;
  const int kt1 = min(kt0 + 8, 2 * j + 2);
  const int slot = batch * SLOTS_PER_BATCH + pj + c;

  const int tid  = threadIdx.x;
  const int w    = tid >> 6;
  const int lane = tid & 63;
  const int lc   = lane & 31;
  const int hi   = lane >> 5;

  const unsigned short* Kf_b = Kf + (batch << 20);
  const unsigned short* VT_b = VT + (batch << 20);

  auto stage = [&](int kt) {
#pragma unroll
    for (int it = 0; it < 8; ++it) {
      int id = it * 256 + tid;
      int kr = id >> 5, cb = id & 31;
      gload_lds16(Kf_b + (((kt << 6) + kr) << 8) + (((cb ^ kr) & 31) << 3),
                  sK + id * 8);
      int hd = id >> 3, cb2 = id & 7;
      gload_lds16(VT_b + (hd << 12) + (kt << 6) + (((cb2 ^ (hd >> 2)) & 7) << 3),
                  sV + id * 8);
    }
  };

  f32x16 oacc[8];
  float m_ = -1e30f, accl = 0.f;
#pragma unroll
  for (int n = 0; n < 8; ++n)
#pragma unroll
    for (int r = 0; r < 16; ++r) oacc[n][r] = 0.f;

  for (int kt = kt0; kt < kt1; ++kt) {
    stage(kt);
    __syncthreads();           // K/V staged (vmcnt drained), prev reads done

    // ---- Q base for this wave's q-col (anti-hoisted so loads re-issue)
    int qrow = (batch << 12) + (j << 7) + (w << 5) + lc;
    uintptr_t qv = (uintptr_t)Qf + ((size_t)qrow << 9) + (hi << 4);
    asm volatile("" : "+v"(qv));
    const unsigned short* qp = (const unsigned short*)qv;

    // ---- QK^T (swapped): S^T[k][q], rows k in regs, col q = lane&31
    f32x16 s0, s1;
#pragma unroll
    for (int r = 0; r < 16; ++r) { s0[r] = 0.f; s1[r] = 0.f; }
    __builtin_amdgcn_s_setprio(1);
#pragma unroll
    for (int ks = 0; ks < 16; ++ks) {
      int cc = (ks << 1) + hi;
      v8h qa  = *(const v8h*)(qp + (ks << 4));
      v8h kb0 = *(const v8h*)(sK + (lc << 8) + (((cc ^ lc) & 31) << 3));
      v8h kb1 = *(const v8h*)(sK + ((32 + lc) << 8) + (((cc ^ lc) & 31) << 3));
      s0 = mfma32h(kb0, qa, s0);
      s1 = mfma32h(kb1, qa, s1);
    }
    __builtin_amdgcn_s_setprio(0);

    // ---- causal mask: k = kt*64 + (r&3)+8*(r>>2)+4*hi (+32 for s1)
    const int qg = (j << 7) + (w << 5) + lc;     // sequence-local q
    if ((kt << 6) + 63 > (j << 7) + (w << 5)) {
#pragma unroll
      for (int r = 0; r < 16; ++r) {
        int kl = (kt << 6) + (r & 3) + ((r >> 2) << 3) + (hi << 2);
        if (kl > qg)      s0[r] = -3e38f;
        if (kl + 32 > qg) s1[r] = -3e38f;
      }
    }

    // ---- row max: in-lane over 32 regs + pair-lane combine
    float mx = fmaxf(s0[0], s1[0]);
#pragma unroll
    for (int r = 1; r < 16; ++r) mx = fmaxf(mx, fmaxf(s0[r], s1[r]));
    mx = fmaxf(mx, __shfl_xor(mx, 32));

    // ---- defer-max rescale (THR = 8)
    if (__any(mx > m_ + 8.0f)) {
      float mn = fmaxf(m_, mx);
      float sc = __expf(m_ - mn);
      m_ = mn;
      accl *= sc;
#pragma unroll
      for (int r = 0; r < 16; ++r) {
        float scr = __shfl(sc, (r & 3) + ((r >> 2) << 3) + (hi << 2));
#pragma unroll
        for (int n = 0; n < 8; ++n) oacc[n][r] *= scr;
      }
    }

    // ---- P = exp(S^T - m) in place; lane-local l partial
#pragma unroll
    for (int r = 0; r < 16; ++r) {
      s0[r] = __expf(s0[r] - m_);
      s1[r] = __expf(s1[r] - m_);
      accl += s0[r] + s1[r];
    }

    // ---- build all 4 PV A-fragments up front (s0/s1 die here)
    v8h pa[4];
#pragma unroll
    for (int half = 0; half < 2; ++half) {
      const f32x16& ps = half ? s1 : s0;
#pragma unroll
      for (int t2 = 0; t2 < 2; ++t2) {
        int b = t2 << 3;
        unsigned X0 = pk2h(ps[b + 0], ps[b + 1]);
        unsigned X1 = pk2h(ps[b + 2], ps[b + 3]);
        unsigned Y0 = pk2h(ps[b + 4], ps[b + 5]);
        unsigned Y1 = pk2h(ps[b + 6], ps[b + 7]);
        unsigned xs0 = (unsigned)__shfl_xor((int)X0, 32);
        unsigned xs1 = (unsigned)__shfl_xor((int)X1, 32);
        unsigned ys0 = (unsigned)__shfl_xor((int)Y0, 32);
        unsigned ys1 = (unsigned)__shfl_xor((int)Y1, 32);
        union { unsigned u[4]; v8h h; } pu;
        pu.u[0] = hi ? ys0 : X0;
        pu.u[1] = hi ? ys1 : X1;
        pu.u[2] = hi ? Y0 : xs0;
        pu.u[3] = hi ? Y1 : xs1;
        pa[(half << 1) + t2] = pu.h;
      }
    }

    // ---- PV: O += P @ V
    __builtin_amdgcn_s_setprio(1);
#pragma unroll
    for (int ks2 = 0; ks2 < 4; ++ks2) {
      int cc = (ks2 << 1) + hi;
#pragma unroll
      for (int n = 0; n < 8; ++n) {
        int hd = (n << 5) + lc;
        v8h vb = *(const v8h*)(sV + (hd << 6) + (((cc ^ (hd >> 2)) & 7) << 3));
        oacc[n] = mfma32h(pa[ks2], vb, oacc[n]);
      }
    }
    __builtin_amdgcn_s_setprio(0);

    __syncthreads();           // compute done; buffers free for next stage
  }

  // ---- flush partial: normalized fp16 O/l + (m, l)
  {
    unsigned short* Op = Opart + (size_t)slot * (128 * 256);
    float lt  = accl + __shfl_xor(accl, 32);
    float inv = (lt > 0.f) ? (1.0f / lt) : 0.f;
#pragma unroll
    for (int n = 0; n < 8; ++n) {
#pragma unroll
      for (int r = 0; r < 16; ++r) {
        int crow = (r & 3) + ((r >> 2) << 3) + (hi << 2);
        float invr = __shfl(inv, crow);
        Op[((w << 5) + crow) * 256 + (n << 5) + lc] = f2h(oacc[n][r] * invr);
      }
    }
    if (lane < 32) {
      Mpart[slot * 128 + (w << 5) + lc] = m_;
      Lpart[slot * 128 + (w << 5) + lc] = lt;
    }
  }
}

// ---------------------------------------------------------------------------
// Kernel 4: merge the nch(j) chunk-partials per q-row.
// ---------------------------------------------------------------------------
__global__ __launch_bounds__(256) void merge_kernel(
    const unsigned short* __restrict__ Opart, const float* __restrict__ Mpart,
    const float* __restrict__ Lpart, float* __restrict__ out)
{
  int t = blockIdx.x * 256 + threadIdx.x;     // row*32 + c8
  int row = t >> 5, c8 = t & 31;
  int batch = row >> 12, wi = row & 4095;
  int j = wi >> 7, rloc = wi & 127;
  int q  = j >> 2;
  int pj = 2 * q * (q + 1) + (j - 4 * q) * (q + 1);   // prefix(j)
  int nch = (j + 4) >> 2;
  int sbase = batch * SLOTS_PER_BATCH + pj;

  float M = -1e30f;
  for (int i = 0; i < nch; ++i)
    M = fmaxf(M, Mpart[(sbase + i) * 128 + rloc]);

  float denom = 0.f;
  float r8[8] = {0.f, 0.f, 0.f, 0.f, 0.f, 0.f, 0.f, 0.f};
  for (int i = 0; i < nch; ++i) {
    float mi = Mpart[(sbase + i) * 128 + rloc];
    float li = Lpart[(sbase + i) * 128 + rloc];
    float wgt = __expf(mi - M) * li;
    denom += wgt;
    const unsigned short* Op =
        Opart + ((size_t)(sbase + i) * 128 + rloc) * 256 + (c8 << 3);
    v8h v = *(const v8h*)Op;
#pragma unroll
    for (int qq = 0; qq < 8; ++qq) r8[qq] += wgt * (float)v[qq];
  }
  float inv = 1.0f / denom;
  float* op = out + (size_t)row * 256 + (c8 << 3);
  f32x4 r0, r1;
#pragma unroll
  for (int qq = 0; qq < 4; ++qq) { r0[qq] = r8[qq] * inv; r1[qq] = r8[4 + qq] * inv; }
  *(f32x4*)op = r0;
  *(f32x4*)(op + 4) = r1;
}

// ---------------------------------------------------------------------------
extern "C" void kernel_launch(void* const* d_in, const int* in_sizes, int n_in,
                              void* d_out, int out_size, void* d_ws, size_t ws_size,
                              hipStream_t stream) {
  (void)in_sizes; (void)n_in; (void)out_size; (void)ws_size;
  const float* x  = (const float*)d_in[0];
  const float* Wq = (const float*)d_in[1];
  const float* bq = (const float*)d_in[2];
  const float* Wk = (const float*)d_in[3];
  const float* bk = (const float*)d_in[4];
  const float* Wv = (const float*)d_in[5];
  const float* bv = (const float*)d_in[6];
  float* out = (float*)d_out;

  const int nslots = NB * SLOTS_PER_BATCH;                   // 576
  unsigned short* Qf = (unsigned short*)d_ws;                // [16384][256] fp16
  unsigned short* Kf = Qf + (size_t)NROW * HD;
  unsigned short* VT = Kf + (size_t)NROW * HD;               // [4][256][4096]
  float* Mpart = (float*)(VT + (size_t)NROW * HD);           // [576][128]
  float* Lpart = Mpart + (size_t)nslots * 128;
  // overlap region: prep buffers (dead after proj) share space with Opart
  unsigned short* regionBase = (unsigned short*)(Lpart + (size_t)nslots * 128);
  unsigned short* xh  = regionBase;                          // bf16 [16384][256]
  unsigned short* xl  = xh + (size_t)NROW * HD;
  unsigned short* WTh = xl + (size_t)NROW * HD;              // [3][256][256]
  unsigned short* WTl = WTh + 3 * 65536;
  unsigned short* Opart = regionBase;                        // [576][128][256]

  hipLaunchKernelGGL(prep_x_kernel, dim3(2048), dim3(256), 0, stream,
                     x, xh, xl);
  hipLaunchKernelGGL(prep_w_kernel, dim3(768), dim3(256), 0, stream,
                     Wq, Wk, Wv, WTh, WTl);
  hipLaunchKernelGGL(proj_kernel, dim3(256, 3), dim3(256), 0, stream,
                     xh, xl, WTh, WTl, bq, bk, bv, Qf, Kf, VT);
  hipLaunchKernelGGL(attn_kernel, dim3(NB * SLOTS_PER_BATCH), dim3(256), 0, stream,
                     Qf, Kf, VT, Opart, Mpart, Lpart);
  hipLaunchKernelGGL(merge_kernel, dim3(2048), dim3(256), 0, stream,
                     Opart, Mpart, Lpart, out);
}